// Round 8
// baseline (30.291 us; speedup 1.0000x reference)
//
#include <hip/hip_runtime.h>

#define IN_DIM   2048
#define OUT_DIM  16384
#define NT       256
#define EPS      1e-12f

// out[b][j] = -scale * rnorm_b * WHT2048(x[b])[j & 2047] + bias[j]
// (hadamard = H_16384[:2048,:], H[i][j]=(-1)^popcount(i&j): only j&2047 matters.)
//
// R8: two-kernel split.
//   A: per row, compute c * WHT2048(x[row]) into d_ws (8 MiB). Small traffic.
//   B: pure streaming expansion: out = ws[row][j&2047] + bias[j].
//      Grid-stride, no LDS/barriers, tiny VGPR, deep turnover -> fill-rate.

__device__ __forceinline__ int swz(int e) { return e ^ (((e >> 6) & 7) << 3); }

#define BFLY(m)                                                   \
    _Pragma("unroll")                                             \
    for (int k = 0; k < 8; ++k)                                   \
        if (!(k & (m))) {                                         \
            const float a_ = v[k], b_ = v[k | (m)];               \
            v[k]       = a_ + b_;                                 \
            v[k | (m)] = a_ - b_;                                 \
        }

// ---------------- kernel A: WHT rows -> ws ----------------
__global__ __launch_bounds__(NT, 4) void wht_rows_kernel(
    const float* __restrict__ x,
    const float* __restrict__ scale,
    float* __restrict__ ws)
{
    __shared__ float sA[IN_DIM];
    __shared__ float sB[IN_DIM];
    __shared__ float red[NT / 64];

    const int b = blockIdx.x;
    const int t = threadIdx.x;
    const int l = t & 63;
    const int w = t >> 6;

    const float4* xr4 = (const float4*)(x + (size_t)b * IN_DIM);
    const float4 a0 = xr4[2 * t];
    const float4 a1 = xr4[2 * t + 1];

    const float negscale = -scale[0];

    float v[8] = {a0.x, a0.y, a0.z, a0.w, a1.x, a1.y, a1.z, a1.w};

    // sum of squares (wave shuffle; cross-wave via red[], read post-barrier)
    float local = 0.f;
#pragma unroll
    for (int k = 0; k < 8; ++k) local = fmaf(v[k], v[k], local);
#pragma unroll
    for (int off = 32; off > 0; off >>= 1)
        local += __shfl_down(local, off, 64);
    if (l == 0) red[w] = local;

    // bits 0-2 in registers
    BFLY(1) BFLY(2) BFLY(4)

    // wave-local round trip 1: write e=8t+k, read bits 3-5
    {
        const int base = swz(t << 3);
        *(float4*)&sA[base]     = make_float4(v[0], v[1], v[2], v[3]);
        *(float4*)&sA[base + 4] = make_float4(v[4], v[5], v[6], v[7]);
    }
    const int bB = (w << 9) | ((l >> 3) << 6) | (l & 7);
#pragma unroll
    for (int k = 0; k < 8; ++k) v[k] = sA[swz(bB | (k << 3))];
    BFLY(1) BFLY(2) BFLY(4)                      // bits 3-5

    // wave-local round trip 2: write back, read bits 6-8
#pragma unroll
    for (int k = 0; k < 8; ++k) sA[swz(bB | (k << 3))] = v[k];
    const int bC = (w << 9) | l;
#pragma unroll
    for (int k = 0; k < 8; ++k) v[k] = sA[swz(bC | (k << 6))];
    BFLY(1) BFLY(2) BFLY(4)                      // bits 6-8

    // final: linear sB[n2*512 + n9] = WHT512(chunk n2)[n9]
#pragma unroll
    for (int k = 0; k < 8; ++k) sB[bC | (k << 6)] = v[k];

    asm volatile("s_waitcnt lgkmcnt(0)" ::: "memory");
    __builtin_amdgcn_s_barrier();

    const float sumsq = red[0] + red[1] + red[2] + red[3];
    const float c = negscale * rsqrtf(fmaxf(sumsq, EPS));

    // bits 9-10: G[n2] = sB4[q + n2*128], q = t&127
    const float4* sB4 = (const float4*)sB;
    const int q = t & 127;
    const float4 G0 = sB4[q];
    const float4 G1 = sB4[q + 128];
    const float4 G2 = sB4[q + 256];
    const float4 G3 = sB4[q + 384];

    float4 s01, d01, s23, d23;
    s01.x = G0.x + G1.x; s01.y = G0.y + G1.y; s01.z = G0.z + G1.z; s01.w = G0.w + G1.w;
    d01.x = G0.x - G1.x; d01.y = G0.y - G1.y; d01.z = G0.z - G1.z; d01.w = G0.w - G1.w;
    s23.x = G2.x + G3.x; s23.y = G2.y + G3.y; s23.z = G2.z + G3.z; s23.w = G2.w + G3.w;
    d23.x = G2.x - G3.x; d23.y = G2.y - G3.y; d23.z = G2.z - G3.z; d23.w = G2.w - G3.w;

    // w_e -> within-row float4 m4 = t; w_o -> m4 = t + 256 (verified mapping)
    const bool hi = (t >= 128);
    const float4 A = hi ? d01 : s01;
    const float4 B = hi ? d23 : s23;
    float4 w_e, w_o;
    w_e.x = c * (A.x + B.x); w_e.y = c * (A.y + B.y);
    w_e.z = c * (A.z + B.z); w_e.w = c * (A.w + B.w);
    w_o.x = c * (A.x - B.x); w_o.y = c * (A.y - B.y);
    w_o.z = c * (A.z - B.z); w_o.w = c * (A.w - B.w);

    float4* ws4 = (float4*)ws + ((size_t)b << 9);
    ws4[t]       = w_e;
    ws4[t + 256] = w_o;
}

// ---------------- kernel B: streaming expansion ----------------
__global__ __launch_bounds__(NT, 8) void expand_kernel(
    const float* __restrict__ ws,
    const float* __restrict__ bias,
    float* __restrict__ out,
    int total4)            // batch * 4096 float4s
{
    const float4* ws4   = (const float4*)ws;
    const float4* bias4 = (const float4*)bias;
    float4* out4        = (float4*)out;

    const int stride = gridDim.x * NT;
    for (int idx = blockIdx.x * NT + threadIdx.x; idx < total4; idx += stride) {
        const int m4  = idx & 4095;              // float4 within row
        const int row = idx >> 12;
        const float4 wv = ws4[(row << 9) | (m4 & 511)];
        const float4 bv = bias4[m4];
        float4 o;
        o.x = wv.x + bv.x;
        o.y = wv.y + bv.y;
        o.z = wv.z + bv.z;
        o.w = wv.w + bv.w;
        out4[idx] = o;
    }
}

extern "C" void kernel_launch(void* const* d_in, const int* in_sizes, int n_in,
                              void* d_out, int out_size, void* d_ws, size_t ws_size,
                              hipStream_t stream) {
    const float* x     = (const float*)d_in[0];
    const float* scale = (const float*)d_in[1];
    const float* bias  = (const float*)d_in[2];
    // d_in[3] (dense hadamard) unused: structure exploited in-kernel.
    float* out = (float*)d_out;
    float* ws  = (float*)d_ws;        // needs batch*2048*4 = 8 MiB

    const int batch = in_sizes[0] / IN_DIM;   // 1024
    wht_rows_kernel<<<batch, NT, 0, stream>>>(x, scale, ws);

    const int total4 = batch * (OUT_DIM / 4);
    expand_kernel<<<2048, NT, 0, stream>>>(ws, bias, out, total4);
}

// Round 9
// 21.174 us; speedup vs baseline: 1.4306x; 1.4306x over previous
//
#include <hip/hip_runtime.h>

#define IN_DIM   2048
#define OUT_DIM  16384
#define EPS      1e-12f

// out[b][j] = -scale * rnorm_b * WHT2048(x[b])[j & 2047] + bias[j]
// (hadamard = H_16384[:2048,:], H[i][j]=(-1)^popcount(i&j): only j&2047 matters.)
//
// R9: one independent 64-lane wave per row. NO barriers, NO LDS -> waves
// self-stagger like a fill kernel (the only structure measured at 7 TB/s).
// Lane l holds 8 float4s: element e = (k4<<8) | (l<<2) | j, reg r=(k4<<2)|j.
//   - e-bits {0,1,8,9,10} = reg bits {0,1,2,3,4}: in-register butterflies
//   - e-bits {2..7} = lane bits: 6 __shfl_xor stages
// Stores: 8 copies x 8 float4/lane, 1 KiB/instr lane-contiguous.

__global__ __launch_bounds__(64) void had_wave_kernel(
    const float* __restrict__ x,
    const float* __restrict__ scale,
    const float* __restrict__ bias,
    float* __restrict__ out)
{
    const int row = blockIdx.x;
    const int l   = threadIdx.x;          // 0..63

    // ---- load row: 8 x b128, e = (k4<<8)|(l<<2)|j  -> v[(k4<<2)|j]
    const float4* xr4 = (const float4*)(x + (size_t)row * IN_DIM);
    float v[32];
#pragma unroll
    for (int k4 = 0; k4 < 8; ++k4) {
        const float4 L = xr4[(k4 << 6) | l];
        v[k4 * 4 + 0] = L.x;
        v[k4 * 4 + 1] = L.y;
        v[k4 * 4 + 2] = L.z;
        v[k4 * 4 + 3] = L.w;
    }

    // ---- sum of squares: 32 fma + 6-step wave butterfly (all lanes get it)
    float local = 0.f;
#pragma unroll
    for (int r = 0; r < 32; ++r) local = fmaf(v[r], v[r], local);
#pragma unroll
    for (int m = 1; m < 64; m <<= 1)
        local += __shfl_xor(local, m, 64);
    const float c = -scale[0] * rsqrtf(fmaxf(local, EPS));

    // ---- FWHT: 5 in-register stages (e-bits 0,1,8,9,10)
#pragma unroll
    for (int m = 1; m < 32; m <<= 1) {
#pragma unroll
        for (int r = 0; r < 32; ++r)
            if (!(r & m)) {
                const float a_ = v[r], b_ = v[r | m];
                v[r]     = a_ + b_;
                v[r | m] = a_ - b_;
            }
    }

    // ---- FWHT: 6 cross-lane stages (e-bits 2..7 = lane bits)
#pragma unroll
    for (int m = 1; m < 64; m <<= 1) {
#pragma unroll
        for (int r = 0; r < 32; ++r) {
            const float o = __shfl_xor(v[r], m, 64);
            v[r] = (l & m) ? (o - v[r]) : (v[r] + o);
        }
    }

    // ---- scale once in registers
#pragma unroll
    for (int r = 0; r < 32; ++r) v[r] *= c;

    // ---- stores: 8 tiled copies; float4-idx = cpy*512 + k4*64 + l
    const float4* bias4 = (const float4*)bias;
    float4* out4        = (float4*)(out + (size_t)row * OUT_DIM);
#pragma unroll
    for (int cpy = 0; cpy < 8; ++cpy) {
#pragma unroll
        for (int k4 = 0; k4 < 8; ++k4) {
            const int idx = cpy * 512 + (k4 << 6) + l;
            const float4 bv = bias4[idx & 4095];
            float4 o;
            o.x = v[k4 * 4 + 0] + bv.x;
            o.y = v[k4 * 4 + 1] + bv.y;
            o.z = v[k4 * 4 + 2] + bv.z;
            o.w = v[k4 * 4 + 3] + bv.w;
            out4[idx] = o;
        }
    }
}

extern "C" void kernel_launch(void* const* d_in, const int* in_sizes, int n_in,
                              void* d_out, int out_size, void* d_ws, size_t ws_size,
                              hipStream_t stream) {
    const float* x     = (const float*)d_in[0];
    const float* scale = (const float*)d_in[1];
    const float* bias  = (const float*)d_in[2];
    // d_in[3] (dense hadamard) unused: structure exploited in-kernel.
    float* out = (float*)d_out;

    const int batch = in_sizes[0] / IN_DIM;   // 1024
    had_wave_kernel<<<batch, 64, 0, stream>>>(x, scale, bias, out);
}

// Round 10
// 17.605 us; speedup vs baseline: 1.7206x; 1.2027x over previous
//
#include <hip/hip_runtime.h>

#define IN_DIM   2048
#define OUT_DIM  16384
#define NT       256
#define EPS      1e-12f

typedef float f32x4 __attribute__((ext_vector_type(4)));

// out[b][j] = -scale * rnorm_b * WHT2048(x[b])[j & 2047] + bias[j]
// (hadamard = H_16384[:2048,:], H[i][j]=(-1)^popcount(i&j): only j&2047 matters.)
//
// R10 = R5 with peak VGPR pressure cut below the launch_bounds(256,4) cap of
// 128: only bias tiles 0-7 are hoisted (32 VGPR); tiles 8-15 are loaded right
// after the post-barrier combine, hiding under the first 8 stores. R5/R6 held
// ~130 live VGPRs -> likely scratch spills injected into the store window.

__device__ __forceinline__ int swz(int e) { return e ^ (((e >> 6) & 7) << 3); }

#define BFLY(m)                                                   \
    _Pragma("unroll")                                             \
    for (int k = 0; k < 8; ++k)                                   \
        if (!(k & (m))) {                                         \
            const float a_ = v[k], b_ = v[k | (m)];               \
            v[k]       = a_ + b_;                                 \
            v[k | (m)] = a_ - b_;                                 \
        }

__global__ __launch_bounds__(NT, 4) void had_fwht_kernel(
    const float* __restrict__ x,
    const float* __restrict__ scale,
    const float* __restrict__ bias,
    float* __restrict__ out)
{
    __shared__ float sA[IN_DIM];   // swizzled wave-local shuffle space
    __shared__ float sB[IN_DIM];   // linear, for the fused output read
    __shared__ float red[NT / 64];

    const int b = blockIdx.x;
    const int t = threadIdx.x;
    const int l = t & 63;
    const int w = t >> 6;

    // ---- x row: thread owns elements 8t..8t+7
    const float4* xr4 = (const float4*)(x + (size_t)b * IN_DIM);
    const float4 a0 = xr4[2 * t];
    const float4 a1 = xr4[2 * t + 1];

    // ---- hoist ONLY bias tiles 0-7 (32 VGPR)
    const float4* bias4 = (const float4*)bias;
    float4 bj[8];
#pragma unroll
    for (int i = 0; i < 8; ++i) bj[i] = bias4[t + i * NT];

    const float negscale = -scale[0];

    float v[8] = {a0.x, a0.y, a0.z, a0.w, a1.x, a1.y, a1.z, a1.w};

    // ---- sum of squares: wave shuffle; cross-wave via red[] (read post-barrier)
    float local = 0.f;
#pragma unroll
    for (int k = 0; k < 8; ++k) local = fmaf(v[k], v[k], local);
#pragma unroll
    for (int off = 32; off > 0; off >>= 1)
        local += __shfl_down(local, off, 64);
    if (l == 0) red[w] = local;

    // ---- bits 0-2 in registers
    BFLY(1) BFLY(2) BFLY(4)

    // ---- wave-local round trip 1: write e=8t+k (2x b128), read bits 3-5
    {
        const int base = swz(t << 3);            // swz keeps low 3 bits: 16B-aligned
        *(float4*)&sA[base]     = make_float4(v[0], v[1], v[2], v[3]);
        *(float4*)&sA[base + 4] = make_float4(v[4], v[5], v[6], v[7]);
    }
    const int bB = (w << 9) | ((l >> 3) << 6) | (l & 7);
#pragma unroll
    for (int k = 0; k < 8; ++k) v[k] = sA[swz(bB | (k << 3))];
    BFLY(1) BFLY(2) BFLY(4)                      // bits 3-5

    // ---- wave-local round trip 2: write back, read bits 6-8
#pragma unroll
    for (int k = 0; k < 8; ++k) sA[swz(bB | (k << 3))] = v[k];
    const int bC = (w << 9) | l;
#pragma unroll
    for (int k = 0; k < 8; ++k) v[k] = sA[swz(bC | (k << 6))];
    BFLY(1) BFLY(2) BFLY(4)                      // bits 6-8

    // ---- final: linear sB at element (w<<9)|(k<<6)|l  (2-way banks, free)
#pragma unroll
    for (int k = 0; k < 8; ++k) sB[bC | (k << 6)] = v[k];

    // ---- the ONLY barrier (LDS drain only)
    asm volatile("s_waitcnt lgkmcnt(0)" ::: "memory");
    __builtin_amdgcn_s_barrier();

    const float sumsq = red[0] + red[1] + red[2] + red[3];
    const float c = negscale * rsqrtf(fmaxf(sumsq, EPS));

    // ---- bits 9-10 fused; G/s/d temporaries die before the store phase
    float4 w_e, w_o;
    {
        const float4* sB4 = (const float4*)sB;
        const int q = t & 127;
        const float4 G0 = sB4[q];
        const float4 G1 = sB4[q + 128];
        const float4 G2 = sB4[q + 256];
        const float4 G3 = sB4[q + 384];

        float4 s01, d01, s23, d23;
        s01.x = G0.x + G1.x; s01.y = G0.y + G1.y; s01.z = G0.z + G1.z; s01.w = G0.w + G1.w;
        d01.x = G0.x - G1.x; d01.y = G0.y - G1.y; d01.z = G0.z - G1.z; d01.w = G0.w - G1.w;
        s23.x = G2.x + G3.x; s23.y = G2.y + G3.y; s23.z = G2.z + G3.z; s23.w = G2.w + G3.w;
        d23.x = G2.x - G3.x; d23.y = G2.y - G3.y; d23.z = G2.z - G3.z; d23.w = G2.w - G3.w;

        const bool hi = (t >= 128);
        const float4 A = hi ? d01 : s01;
        const float4 B = hi ? d23 : s23;
        w_e.x = A.x + B.x; w_e.y = A.y + B.y; w_e.z = A.z + B.z; w_e.w = A.w + B.w;
        w_o.x = A.x - B.x; w_o.y = A.y - B.y; w_o.z = A.z - B.z; w_o.w = A.w - B.w;
    }

    // ---- issue second-half bias loads NOW: they fly under the first 8 stores
    float4 b2[8];
#pragma unroll
    for (int i = 0; i < 8; ++i) b2[i] = bias4[t + (i + 8) * NT];

    // ---- stores: lane-contiguous 1 KiB/instr, nontemporal
    f32x4* orow = (f32x4*)(out + (size_t)b * OUT_DIM);
#pragma unroll
    for (int i = 0; i < 8; ++i) {
        const float4 ws = (i & 1) ? w_o : w_e;
        f32x4 o;
        o.x = fmaf(c, ws.x, bj[i].x);
        o.y = fmaf(c, ws.y, bj[i].y);
        o.z = fmaf(c, ws.z, bj[i].z);
        o.w = fmaf(c, ws.w, bj[i].w);
        __builtin_nontemporal_store(o, &orow[t + i * NT]);
    }
#pragma unroll
    for (int i = 0; i < 8; ++i) {
        const float4 ws = (i & 1) ? w_o : w_e;   // (i+8)&1 == i&1... careful: (i+8) parity == i parity
        f32x4 o;
        o.x = fmaf(c, ws.x, b2[i].x);
        o.y = fmaf(c, ws.y, b2[i].y);
        o.z = fmaf(c, ws.z, b2[i].z);
        o.w = fmaf(c, ws.w, b2[i].w);
        __builtin_nontemporal_store(o, &orow[t + (i + 8) * NT]);
    }
}

extern "C" void kernel_launch(void* const* d_in, const int* in_sizes, int n_in,
                              void* d_out, int out_size, void* d_ws, size_t ws_size,
                              hipStream_t stream) {
    const float* x     = (const float*)d_in[0];
    const float* scale = (const float*)d_in[1];
    const float* bias  = (const float*)d_in[2];
    // d_in[3] (dense hadamard) unused: structure exploited in-kernel.
    float* out = (float*)d_out;

    const int batch = in_sizes[0] / IN_DIM;   // 1024
    had_fwht_kernel<<<batch, NT, 0, stream>>>(x, scale, bias, out);
}